// Round 11
// baseline (8885.892 us; speedup 1.0000x reference)
//
#include <hip/hip_runtime.h>

typedef unsigned short u16;
typedef _Float16 f16;
typedef __attribute__((ext_vector_type(8))) _Float16 f16x8;
typedef __attribute__((ext_vector_type(8))) unsigned short u16x8;
typedef __attribute__((ext_vector_type(4))) float f32x4;
typedef __attribute__((ext_vector_type(4))) unsigned u32x4;

#define NWGT 64  // 32 WGs layer-0 + 32 WGs layer-1

// returns hi f16 bits in [15:0], lo f16 bits (residual * 2048) in [31:16]
__device__ __forceinline__ unsigned split2(float v) {
  f16 h = (f16)v;
  f16 l2 = (f16)((v - (float)h) * 2048.0f);
  return (unsigned)__builtin_bit_cast(u16, h) | ((unsigned)__builtin_bit_cast(u16, l2) << 16);
}

__global__ void k_zero(unsigned* __restrict__ flg) {
  int i = blockIdx.x * blockDim.x + threadIdx.x;
  if (i < 2048) flg[i] = 0u;
}

// ---- x fp32 -> packed u32 (hi | lo<<16) ----
__global__ void k_xsplit(const float* __restrict__ in, unsigned* __restrict__ out, int n) {
  for (int i = blockIdx.x * blockDim.x + threadIdx.x; i < n; i += gridDim.x * blockDim.x)
    out[i] = split2(in[i]);
}

// ---- pack W [512][2048] fp32 into MFMA-B fragment order, hi+lo planes ----
// frag layout: [g(32)][q(4)][kc(16)][lane(64)][8] u16
__global__ void k_pack(const float* __restrict__ W, u16* __restrict__ hi, u16* __restrict__ lo) {
  int idx = blockIdx.x * blockDim.x + threadIdx.x; // 131072
  int lane = idx & 63, kc = (idx >> 6) & 15, q = (idx >> 10) & 3, g = idx >> 12; // g<32
  int gcol = g * 16 + (lane & 15) + q * 512;
  int kb = kc * 32 + ((lane >> 4) << 3);
  u16x8 oh, ol;
#pragma unroll
  for (int j = 0; j < 8; ++j) {
    unsigned s = split2(W[(size_t)(kb + j) * 2048 + gcol]);
    oh[j] = (u16)s;
    ol[j] = (u16)(s >> 16);
  }
  *(u16x8*)(hi + (size_t)idx * 8) = oh;
  *(u16x8*)(lo + (size_t)idx * 8) = ol;
}

// unpack 8 packed u32 -> hi f16x8, lo f16x8
__device__ __forceinline__ void unpk(uint4 a, uint4 b, f16x8& hi, f16x8& lo) {
  u32x4 H, L;
  H[0] = __builtin_amdgcn_perm(a.y, a.x, 0x05040100u);
  H[1] = __builtin_amdgcn_perm(a.w, a.z, 0x05040100u);
  H[2] = __builtin_amdgcn_perm(b.y, b.x, 0x05040100u);
  H[3] = __builtin_amdgcn_perm(b.w, b.z, 0x05040100u);
  L[0] = __builtin_amdgcn_perm(a.y, a.x, 0x07060302u);
  L[1] = __builtin_amdgcn_perm(a.w, a.z, 0x07060302u);
  L[2] = __builtin_amdgcn_perm(b.y, b.x, 0x07060302u);
  L[3] = __builtin_amdgcn_perm(b.w, b.z, 0x07060302u);
  hi = __builtin_bit_cast(f16x8, H);
  lo = __builtin_bit_cast(f16x8, L);
}

// ---- fused 2-layer pipelined LSTM scan: 64 WGs, 257 rounds, 2 barriers/round ----
// WGs 0..31 = layer 0 (step t=s), WGs 32..63 = layer 1 (step t=s-1).
// Phase A (before barrier-1): yx = x@wx_slice, yh = h@wh_slice (split fp16, hi frags in
// LDS, lo frags streamed from L2); publish LN partials for both sets.
// Barrier-1; stats readback (contiguous [row][g] slices, fixed-order deterministic sum);
// phase B: gates, c/h update, publish packed h. Barrier-2 (outputs overlap poll).
__global__ void __launch_bounds__(256, 1) k_scan7(
    const unsigned* __restrict__ xs, const u16* __restrict__ frg,
    const float* __restrict__ gx, const float* __restrict__ bx,
    const float* __restrict__ gh, const float* __restrict__ bh,
    const float* __restrict__ bias,
    const float* __restrict__ h0, const float* __restrict__ c0,
    unsigned* __restrict__ hpub0, unsigned* __restrict__ hpub1,
    unsigned long long* __restrict__ part, unsigned* __restrict__ flags,
    float* __restrict__ out) {
  __shared__ u16 pkh[32768]; // wh_hi frag slice (64KB)
  __shared__ u16 pkx[32768]; // wx_hi frag slice (64KB)
  __shared__ float musd[256];
  const int tid = threadIdx.x;
  const int l = tid & 63, w = tid >> 6;
  const int g = blockIdx.x;
  const int layer = g >> 5, gg = g & 31;
  const int lq = l >> 4, ll = l & 15;
  const int hcol = gg * 16 + ll;
  const bool l0 = (layer == 0);

  const u16* whh_g = frg + (size_t)(layer * 4 + 0) * 1048576 + (size_t)gg * 32768;
  const u16* whl_g = frg + (size_t)(layer * 4 + 1) * 1048576 + (size_t)gg * 32768;
  const u16* wxh_g = frg + (size_t)(layer * 4 + 2) * 1048576 + (size_t)gg * 32768;
  const u16* wxl_g = frg + (size_t)(layer * 4 + 3) * 1048576 + (size_t)gg * 32768;
  for (int c = tid; c < 4096; c += 256) {
    *(u16x8*)(pkh + (size_t)c * 8) = *(const u16x8*)(whh_g + (size_t)c * 8);
    *(u16x8*)(pkx + (size_t)c * 8) = *(const u16x8*)(wxh_g + (size_t)c * 8);
  }
  float gxv[4], bxv[4], ghv[4], bhv[4], biv[4];
#pragma unroll
  for (int q = 0; q < 4; ++q) {
    int gc = layer * 2048 + hcol + q * 512;
    gxv[q] = gx[gc]; bxv[q] = bx[gc]; ghv[q] = gh[gc]; bhv[q] = bh[gc]; biv[q] = bias[gc];
  }
  float cr[4];
#pragma unroll
  for (int j = 0; j < 4; ++j)
    cr[j] = c0[layer * 32768 + (w * 16 + lq * 4 + j) * 512 + hcol];
  unsigned* myhp = l0 ? hpub0 : hpub1;
  for (int u = tid; u < 1024; u += 256) {
    int row = 2 * gg + (u >> 9), col = u & 511;
    __hip_atomic_store(&myhp[row * 512 + col], split2(h0[layer * 32768 + row * 512 + col]),
                       __ATOMIC_RELAXED, __HIP_MEMORY_SCOPE_AGENT);
  }
  unsigned bid = 0;
#define BAR_ARRIVE()                                                                         \
  do {                                                                                       \
    bid++;                                                                                   \
    asm volatile("s_waitcnt vmcnt(0)" ::: "memory");                                         \
    __syncthreads();                                                                         \
    if (tid == 0)                                                                            \
      __hip_atomic_store(&flags[g * 32], bid, __ATOMIC_RELAXED, __HIP_MEMORY_SCOPE_AGENT);   \
  } while (0)
#define BAR_WAIT()                                                                           \
  do {                                                                                       \
    if (tid < NWGT)                                                                          \
      while (__hip_atomic_load(&flags[tid * 32], __ATOMIC_RELAXED,                           \
                               __HIP_MEMORY_SCOPE_AGENT) < bid) {}                           \
    __builtin_amdgcn_fence(__ATOMIC_ACQUIRE, "agent");                                       \
  } while (0)

  BAR_ARRIVE();
  BAR_WAIT();
  __syncthreads();

  for (int s = 0; s < 257; ++s) {
    const int t = l0 ? s : s - 1;
    const bool act = l0 ? (s < 256) : (s >= 1);
    const int p = s & 1;
    float yx[4][4], yh[4][4];
    if (act) {
      // ---- phase A: two split-fp16 matmuls ----
      const unsigned* xbase = l0 ? (xs + (size_t)t * 32768) : hpub0;
      const unsigned* hbase = l0 ? hpub0 : hpub1;
      f32x4 ax0[4] = {}, ax1[4] = {}, ah0[4] = {}, ah1[4] = {};
#pragma unroll
      for (int kc = 0; kc < 16; ++kc) {
        size_t aoff = (size_t)(w * 16 + ll) * 512 + kc * 32 + lq * 8;
        uint4 xa = *(const uint4*)(xbase + aoff), xb = *(const uint4*)(xbase + aoff + 4);
        uint4 ha = *(const uint4*)(hbase + aoff), hb = *(const uint4*)(hbase + aoff + 4);
        f16x8 xah, xal, hah, hal;
        unpk(xa, xb, xah, xal);
        unpk(ha, hb, hah, hal);
#pragma unroll
        for (int q = 0; q < 4; ++q) {
          size_t fo = ((size_t)(q * 16 + kc) * 64 + l) * 8;
          f16x8 wxhf = *(const f16x8*)(pkx + fo);
          f16x8 wxlf = *(const f16x8*)(wxl_g + fo);
          f16x8 whhf = *(const f16x8*)(pkh + fo);
          f16x8 whlf = *(const f16x8*)(whl_g + fo);
          ax0[q] = __builtin_amdgcn_mfma_f32_16x16x32_f16(xah, wxhf, ax0[q], 0, 0, 0);
          ax1[q] = __builtin_amdgcn_mfma_f32_16x16x32_f16(xah, wxlf, ax1[q], 0, 0, 0);
          ax1[q] = __builtin_amdgcn_mfma_f32_16x16x32_f16(xal, wxhf, ax1[q], 0, 0, 0);
          ah0[q] = __builtin_amdgcn_mfma_f32_16x16x32_f16(hah, whhf, ah0[q], 0, 0, 0);
          ah1[q] = __builtin_amdgcn_mfma_f32_16x16x32_f16(hah, whlf, ah1[q], 0, 0, 0);
          ah1[q] = __builtin_amdgcn_mfma_f32_16x16x32_f16(hal, whhf, ah1[q], 0, 0, 0);
        }
      }
#pragma unroll
      for (int q = 0; q < 4; ++q)
#pragma unroll
        for (int j = 0; j < 4; ++j) {
          yx[q][j] = ax0[q][j] + ax1[q][j] * (1.0f / 2048.0f);
          yh[q][j] = ah0[q][j] + ah1[q][j] * (1.0f / 2048.0f);
        }
      // partial LN stats (two sets), 16-lane reduce, publish as u64 stores
      float s1x[4], s2x[4], s1h[4], s2h[4];
#pragma unroll
      for (int j = 0; j < 4; ++j) {
        s1x[j] = yx[0][j] + yx[1][j] + yx[2][j] + yx[3][j];
        s2x[j] = yx[0][j] * yx[0][j] + yx[1][j] * yx[1][j] + yx[2][j] * yx[2][j] + yx[3][j] * yx[3][j];
        s1h[j] = yh[0][j] + yh[1][j] + yh[2][j] + yh[3][j];
        s2h[j] = yh[0][j] * yh[0][j] + yh[1][j] * yh[1][j] + yh[2][j] * yh[2][j] + yh[3][j] * yh[3][j];
      }
#pragma unroll
      for (int m = 1; m <= 8; m <<= 1)
#pragma unroll
        for (int j = 0; j < 4; ++j) {
          s1x[j] += __shfl_xor(s1x[j], m, 64);
          s2x[j] += __shfl_xor(s2x[j], m, 64);
          s1h[j] += __shfl_xor(s1h[j], m, 64);
          s2h[j] += __shfl_xor(s2h[j], m, 64);
        }
      if (ll == 0) {
#pragma unroll
        for (int j = 0; j < 4; ++j) {
          int r = w * 16 + lq * 4 + j;
          size_t bx_ = ((((size_t)layer * 2 + p) * 2 + 0) * 64 + r) * 32 + gg;
          size_t bh_ = ((((size_t)layer * 2 + p) * 2 + 1) * 64 + r) * 32 + gg;
          unsigned long long vx = ((unsigned long long)__builtin_bit_cast(unsigned, s2x[j]) << 32) |
                                  (unsigned long long)__builtin_bit_cast(unsigned, s1x[j]);
          unsigned long long vh = ((unsigned long long)__builtin_bit_cast(unsigned, s2h[j]) << 32) |
                                  (unsigned long long)__builtin_bit_cast(unsigned, s1h[j]);
          __hip_atomic_store(&part[bx_], vx, __ATOMIC_RELAXED, __HIP_MEMORY_SCOPE_AGENT);
          __hip_atomic_store(&part[bh_], vh, __ATOMIC_RELAXED, __HIP_MEMORY_SCOPE_AGENT);
        }
      }
    }
    // ---- barrier 1 ----
    BAR_ARRIVE();
    BAR_WAIT();
    float hs[4];
    if (act) {
      if (tid < 64) {
        const uint4* px = (const uint4*)(part + ((((size_t)layer * 2 + p) * 2 + 0) * 64 + tid) * 32);
        const uint4* ph = (const uint4*)(part + ((((size_t)layer * 2 + p) * 2 + 1) * 64 + tid) * 32);
        float a1x = 0.f, a2x = 0.f, a1h = 0.f, a2h = 0.f;
#pragma unroll
        for (int i = 0; i < 16; ++i) { // fixed order -> deterministic
          uint4 vx = px[i], vh = ph[i];
          a1x += __builtin_bit_cast(float, vx.x); a2x += __builtin_bit_cast(float, vx.y);
          a1x += __builtin_bit_cast(float, vx.z); a2x += __builtin_bit_cast(float, vx.w);
          a1h += __builtin_bit_cast(float, vh.x); a2h += __builtin_bit_cast(float, vh.y);
          a1h += __builtin_bit_cast(float, vh.z); a2h += __builtin_bit_cast(float, vh.w);
        }
        float mux = a1x * (1.f / 2048.f), ex2x = a2x * (1.f / 2048.f);
        float muh = a1h * (1.f / 2048.f), ex2h = a2h * (1.f / 2048.f);
        musd[tid] = mux;
        musd[64 + tid] = 1.0f / sqrtf(ex2x - mux * mux + 1e-5f);
        musd[128 + tid] = muh;
        musd[192 + tid] = 1.0f / sqrtf(ex2h - muh * muh + 1e-5f);
      }
      __syncthreads();
      // ---- phase B: gates, state update, publish h ----
#pragma unroll
      for (int j = 0; j < 4; ++j) {
        int r = w * 16 + lq * 4 + j;
        float mux = musd[r], rsx = musd[64 + r], muh = musd[128 + r], rsh = musd[192 + r];
        float gv[4];
#pragma unroll
        for (int q = 0; q < 4; ++q)
          gv[q] = (yx[q][j] - mux) * rsx * gxv[q] + bxv[q] + biv[q] +
                  (yh[q][j] - muh) * rsh * ghv[q] + bhv[q];
        float fi = 1.f / (1.f + expf(-gv[0]));
        float ff = 1.f / (1.f + expf(-gv[1]));
        float fo = 1.f / (1.f + expf(-gv[2]));
        float fu = tanhf(gv[3]);
        cr[j] = ff * cr[j] + fi * fu;
        float h = fo * tanhf(cr[j]);
        hs[j] = h;
        __hip_atomic_store(&myhp[(size_t)r * 512 + hcol], split2(h),
                           __ATOMIC_RELAXED, __HIP_MEMORY_SCOPE_AGENT);
      }
    }
    // ---- barrier 2; output stores overlap the poll ----
    BAR_ARRIVE();
    if (act) {
#pragma unroll
      for (int j = 0; j < 4; ++j) {
        int r = w * 16 + lq * 4 + j;
        size_t ro = (size_t)r * 512 + hcol;
        if (!l0) out[(size_t)t * 32768 + ro] = hs[j];
        if (t == 255) {
          out[8388608 + (size_t)layer * 32768 + ro] = hs[j];
          out[8388608 + 65536 + (size_t)layer * 32768 + ro] = cr[j];
        }
      }
    }
    BAR_WAIT();
    __syncthreads();
  }
#undef BAR_ARRIVE
#undef BAR_WAIT
}

// ---- workspace layout (bytes), total ~50.9 MB ----
#define XS_OFF  0ull         // 256*64*512 u32 packed x = 32MB
#define FRG_OFF 33554432ull  // 8 frag arrays (wh/wx x hi/lo x 2 layers) x 2MB = 16MB
#define HP0_OFF 50331648ull  // 64*512 u32 = 128KB
#define HP1_OFF 50462720ull  // 128KB
#define PRT_OFF 50593792ull  // 2 layer * 2 p * 2 set * 64 row * 32 g * u64 = 256KB
#define FLG_OFF 50855936ull  // 2048 u32 = 8KB

extern "C" void kernel_launch(void* const* d_in, const int* in_sizes, int n_in,
                              void* d_out, int out_size, void* d_ws, size_t ws_size,
                              hipStream_t stream) {
  const float* inputs = (const float*)d_in[0];
  const float* h0 = (const float*)d_in[1];
  const float* c0 = (const float*)d_in[2];
  const float* wx = (const float*)d_in[3];
  const float* wh = (const float*)d_in[4];
  const float* bias = (const float*)d_in[5];
  const float* gxp = (const float*)d_in[6];
  const float* bxp = (const float*)d_in[7];
  const float* ghp = (const float*)d_in[8];
  const float* bhp = (const float*)d_in[9];
  float* out = (float*)d_out;
  char* ws = (char*)d_ws;

  unsigned* xs = (unsigned*)(ws + XS_OFF);
  u16* frg = (u16*)(ws + FRG_OFF);
  unsigned* hp0 = (unsigned*)(ws + HP0_OFF);
  unsigned* hp1 = (unsigned*)(ws + HP1_OFF);
  unsigned long long* prt = (unsigned long long*)(ws + PRT_OFF);
  unsigned* flg = (unsigned*)(ws + FLG_OFF);

  k_zero<<<8, 256, 0, stream>>>(flg);
  k_xsplit<<<4096, 256, 0, stream>>>(inputs, xs, 8388608);
  for (int l = 0; l < 2; ++l) {
    k_pack<<<512, 256, 0, stream>>>(wh + (size_t)l * 1048576,
                                    frg + (size_t)(l * 4 + 0) * 1048576,
                                    frg + (size_t)(l * 4 + 1) * 1048576);
    k_pack<<<512, 256, 0, stream>>>(wx + (size_t)l * 1048576,
                                    frg + (size_t)(l * 4 + 2) * 1048576,
                                    frg + (size_t)(l * 4 + 3) * 1048576);
  }
  k_scan7<<<NWGT, 256, 0, stream>>>(xs, frg, gxp, bxp, ghp, bhp, bias, h0, c0,
                                    hp0, hp1, prt, flg, out);
}

// Round 12
// 8828.522 us; speedup vs baseline: 1.0065x; 1.0065x over previous
//
#include <hip/hip_runtime.h>

typedef unsigned short u16;
typedef _Float16 f16;
typedef __attribute__((ext_vector_type(8))) _Float16 f16x8;
typedef __attribute__((ext_vector_type(8))) unsigned short u16x8;
typedef __attribute__((ext_vector_type(4))) float f32x4;
typedef __attribute__((ext_vector_type(4))) unsigned u32x4;

#define NWGT 64  // 32 WGs layer-0 + 32 WGs layer-1

// returns hi f16 bits in [15:0], lo f16 bits (residual * 2048) in [31:16]
__device__ __forceinline__ unsigned split2(float v) {
  f16 h = (f16)v;
  f16 l2 = (f16)((v - (float)h) * 2048.0f);
  return (unsigned)__builtin_bit_cast(u16, h) | ((unsigned)__builtin_bit_cast(u16, l2) << 16);
}

__global__ void k_zero(unsigned* __restrict__ flg) {
  int i = blockIdx.x * blockDim.x + threadIdx.x;
  if (i < 2048) flg[i] = 0u;
}

// ---- x fp32 -> packed u32 (hi | lo<<16) ----
__global__ void k_xsplit(const float* __restrict__ in, unsigned* __restrict__ out, int n) {
  for (int i = blockIdx.x * blockDim.x + threadIdx.x; i < n; i += gridDim.x * blockDim.x)
    out[i] = split2(in[i]);
}

// ---- pack W [512][2048] fp32 into MFMA-B fragment order, hi+lo planes ----
// frag layout: [g(32)][q(4)][kc(16)][lane(64)][8] u16
__global__ void k_pack(const float* __restrict__ W, u16* __restrict__ hi, u16* __restrict__ lo) {
  int idx = blockIdx.x * blockDim.x + threadIdx.x; // 131072
  int lane = idx & 63, kc = (idx >> 6) & 15, q = (idx >> 10) & 3, g = idx >> 12; // g<32
  int gcol = g * 16 + (lane & 15) + q * 512;
  int kb = kc * 32 + ((lane >> 4) << 3);
  u16x8 oh, ol;
#pragma unroll
  for (int j = 0; j < 8; ++j) {
    unsigned s = split2(W[(size_t)(kb + j) * 2048 + gcol]);
    oh[j] = (u16)s;
    ol[j] = (u16)(s >> 16);
  }
  *(u16x8*)(hi + (size_t)idx * 8) = oh;
  *(u16x8*)(lo + (size_t)idx * 8) = ol;
}

// unpack 8 packed u32 -> hi f16x8, lo f16x8
__device__ __forceinline__ void unpk(uint4 a, uint4 b, f16x8& hi, f16x8& lo) {
  u32x4 H, L;
  H[0] = __builtin_amdgcn_perm(a.y, a.x, 0x05040100u);
  H[1] = __builtin_amdgcn_perm(a.w, a.z, 0x05040100u);
  H[2] = __builtin_amdgcn_perm(b.y, b.x, 0x05040100u);
  H[3] = __builtin_amdgcn_perm(b.w, b.z, 0x05040100u);
  L[0] = __builtin_amdgcn_perm(a.y, a.x, 0x07060302u);
  L[1] = __builtin_amdgcn_perm(a.w, a.z, 0x07060302u);
  L[2] = __builtin_amdgcn_perm(b.y, b.x, 0x07060302u);
  L[3] = __builtin_amdgcn_perm(b.w, b.z, 0x07060302u);
  hi = __builtin_bit_cast(f16x8, H);
  lo = __builtin_bit_cast(f16x8, L);
}

// ---- fused 2-layer pipelined LSTM scan: 64 WGs, 257 rounds, 2 barriers/round ----
// WGs 0..31 = layer 0 (step t=s), WGs 32..63 = layer 1 (step t=s-1).
// Phase A (before barrier-1): yx = x@wx_slice, yh = h@wh_slice (split fp16, hi frags in
// LDS, lo frags streamed from L2); publish LN partials for both sets.
// Barrier-1; stats readback (contiguous [row][g] slices, fixed-order deterministic sum);
// phase B: gates, c/h update, publish packed h. Barrier-2 (outputs overlap poll).
__global__ void __launch_bounds__(256, 1) k_scan7(
    const unsigned* __restrict__ xs, const u16* __restrict__ frg,
    const float* __restrict__ gx, const float* __restrict__ bx,
    const float* __restrict__ gh, const float* __restrict__ bh,
    const float* __restrict__ bias,
    const float* __restrict__ h0, const float* __restrict__ c0,
    unsigned* __restrict__ hpub0, unsigned* __restrict__ hpub1,
    unsigned long long* __restrict__ part, unsigned* __restrict__ flags,
    float* __restrict__ out) {
  __shared__ u16 pkh[32768]; // wh_hi frag slice (64KB)
  __shared__ u16 pkx[32768]; // wx_hi frag slice (64KB)
  __shared__ float musd[256];
  const int tid = threadIdx.x;
  const int l = tid & 63, w = tid >> 6;
  const int g = blockIdx.x;
  const int layer = g >> 5, gg = g & 31;
  const int lq = l >> 4, ll = l & 15;
  const int hcol = gg * 16 + ll;
  const bool l0 = (layer == 0);

  const u16* whh_g = frg + (size_t)(layer * 4 + 0) * 1048576 + (size_t)gg * 32768;
  const u16* whl_g = frg + (size_t)(layer * 4 + 1) * 1048576 + (size_t)gg * 32768;
  const u16* wxh_g = frg + (size_t)(layer * 4 + 2) * 1048576 + (size_t)gg * 32768;
  const u16* wxl_g = frg + (size_t)(layer * 4 + 3) * 1048576 + (size_t)gg * 32768;
  for (int c = tid; c < 4096; c += 256) {
    *(u16x8*)(pkh + (size_t)c * 8) = *(const u16x8*)(whh_g + (size_t)c * 8);
    *(u16x8*)(pkx + (size_t)c * 8) = *(const u16x8*)(wxh_g + (size_t)c * 8);
  }
  float gxv[4], bxv[4], ghv[4], bhv[4], biv[4];
#pragma unroll
  for (int q = 0; q < 4; ++q) {
    int gc = layer * 2048 + hcol + q * 512;
    gxv[q] = gx[gc]; bxv[q] = bx[gc]; ghv[q] = gh[gc]; bhv[q] = bh[gc]; biv[q] = bias[gc];
  }
  float cr[4];
#pragma unroll
  for (int j = 0; j < 4; ++j)
    cr[j] = c0[layer * 32768 + (w * 16 + lq * 4 + j) * 512 + hcol];
  unsigned* myhp = l0 ? hpub0 : hpub1;
  for (int u = tid; u < 1024; u += 256) {
    int row = 2 * gg + (u >> 9), col = u & 511;
    __hip_atomic_store(&myhp[row * 512 + col], split2(h0[layer * 32768 + row * 512 + col]),
                       __ATOMIC_RELAXED, __HIP_MEMORY_SCOPE_AGENT);
  }
  unsigned bid = 0;
#define BAR_ARRIVE()                                                                         \
  do {                                                                                       \
    bid++;                                                                                   \
    asm volatile("s_waitcnt vmcnt(0)" ::: "memory");                                         \
    __syncthreads();                                                                         \
    if (tid == 0)                                                                            \
      __hip_atomic_store(&flags[g * 32], bid, __ATOMIC_RELAXED, __HIP_MEMORY_SCOPE_AGENT);   \
  } while (0)
#define BAR_WAIT()                                                                           \
  do {                                                                                       \
    if (tid < NWGT)                                                                          \
      while (__hip_atomic_load(&flags[tid * 32], __ATOMIC_RELAXED,                           \
                               __HIP_MEMORY_SCOPE_AGENT) < bid) {}                           \
    __builtin_amdgcn_fence(__ATOMIC_ACQUIRE, "agent");                                       \
  } while (0)

  BAR_ARRIVE();
  BAR_WAIT();
  __syncthreads();

  for (int s = 0; s < 257; ++s) {
    const int t = l0 ? s : s - 1;
    const bool act = l0 ? (s < 256) : (s >= 1);
    const int p = s & 1;
    float yx[4][4], yh[4][4];
    if (act) {
      // ---- phase A: two split-fp16 matmuls ----
      const unsigned* xbase = l0 ? (xs + (size_t)t * 32768) : hpub0;
      const unsigned* hbase = l0 ? hpub0 : hpub1;
      f32x4 ax0[4] = {}, ax1[4] = {}, ah0[4] = {}, ah1[4] = {};
#pragma unroll
      for (int kc = 0; kc < 16; ++kc) {
        size_t aoff = (size_t)(w * 16 + ll) * 512 + kc * 32 + lq * 8;
        uint4 xa = *(const uint4*)(xbase + aoff), xb = *(const uint4*)(xbase + aoff + 4);
        uint4 ha = *(const uint4*)(hbase + aoff), hb = *(const uint4*)(hbase + aoff + 4);
        f16x8 xah, xal, hah, hal;
        unpk(xa, xb, xah, xal);
        unpk(ha, hb, hah, hal);
#pragma unroll
        for (int q = 0; q < 4; ++q) {
          size_t fo = ((size_t)(q * 16 + kc) * 64 + l) * 8;
          f16x8 wxhf = *(const f16x8*)(pkx + fo);
          f16x8 wxlf = *(const f16x8*)(wxl_g + fo);
          f16x8 whhf = *(const f16x8*)(pkh + fo);
          f16x8 whlf = *(const f16x8*)(whl_g + fo);
          ax0[q] = __builtin_amdgcn_mfma_f32_16x16x32_f16(xah, wxhf, ax0[q], 0, 0, 0);
          ax1[q] = __builtin_amdgcn_mfma_f32_16x16x32_f16(xah, wxlf, ax1[q], 0, 0, 0);
          ax1[q] = __builtin_amdgcn_mfma_f32_16x16x32_f16(xal, wxhf, ax1[q], 0, 0, 0);
          ah0[q] = __builtin_amdgcn_mfma_f32_16x16x32_f16(hah, whhf, ah0[q], 0, 0, 0);
          ah1[q] = __builtin_amdgcn_mfma_f32_16x16x32_f16(hah, whlf, ah1[q], 0, 0, 0);
          ah1[q] = __builtin_amdgcn_mfma_f32_16x16x32_f16(hal, whhf, ah1[q], 0, 0, 0);
        }
      }
#pragma unroll
      for (int q = 0; q < 4; ++q)
#pragma unroll
        for (int j = 0; j < 4; ++j) {
          yx[q][j] = ax0[q][j] + ax1[q][j] * (1.0f / 2048.0f);
          yh[q][j] = ah0[q][j] + ah1[q][j] * (1.0f / 2048.0f);
        }
      // partial LN stats (two sets), 16-lane reduce, publish as u64 stores
      float s1x[4], s2x[4], s1h[4], s2h[4];
#pragma unroll
      for (int j = 0; j < 4; ++j) {
        s1x[j] = yx[0][j] + yx[1][j] + yx[2][j] + yx[3][j];
        s2x[j] = yx[0][j] * yx[0][j] + yx[1][j] * yx[1][j] + yx[2][j] * yx[2][j] + yx[3][j] * yx[3][j];
        s1h[j] = yh[0][j] + yh[1][j] + yh[2][j] + yh[3][j];
        s2h[j] = yh[0][j] * yh[0][j] + yh[1][j] * yh[1][j] + yh[2][j] * yh[2][j] + yh[3][j] * yh[3][j];
      }
#pragma unroll
      for (int m = 1; m <= 8; m <<= 1)
#pragma unroll
        for (int j = 0; j < 4; ++j) {
          s1x[j] += __shfl_xor(s1x[j], m, 64);
          s2x[j] += __shfl_xor(s2x[j], m, 64);
          s1h[j] += __shfl_xor(s1h[j], m, 64);
          s2h[j] += __shfl_xor(s2h[j], m, 64);
        }
      if (ll == 0) {
#pragma unroll
        for (int j = 0; j < 4; ++j) {
          int r = w * 16 + lq * 4 + j;
          size_t bx_ = ((((size_t)layer * 2 + p) * 2 + 0) * 64 + r) * 32 + gg;
          size_t bh_ = ((((size_t)layer * 2 + p) * 2 + 1) * 64 + r) * 32 + gg;
          unsigned long long vx = ((unsigned long long)__builtin_bit_cast(unsigned, s2x[j]) << 32) |
                                  (unsigned long long)__builtin_bit_cast(unsigned, s1x[j]);
          unsigned long long vh = ((unsigned long long)__builtin_bit_cast(unsigned, s2h[j]) << 32) |
                                  (unsigned long long)__builtin_bit_cast(unsigned, s1h[j]);
          __hip_atomic_store(&part[bx_], vx, __ATOMIC_RELAXED, __HIP_MEMORY_SCOPE_AGENT);
          __hip_atomic_store(&part[bh_], vh, __ATOMIC_RELAXED, __HIP_MEMORY_SCOPE_AGENT);
        }
      }
    }
    // ---- barrier 1 ----
    BAR_ARRIVE();
    BAR_WAIT();
    float hs[4];
    if (act) {
      if (tid < 64) {
        const uint4* px = (const uint4*)(part + ((((size_t)layer * 2 + p) * 2 + 0) * 64 + tid) * 32);
        const uint4* ph = (const uint4*)(part + ((((size_t)layer * 2 + p) * 2 + 1) * 64 + tid) * 32);
        float a1x = 0.f, a2x = 0.f, a1h = 0.f, a2h = 0.f;
#pragma unroll
        for (int i = 0; i < 16; ++i) { // fixed order -> deterministic
          uint4 vx = px[i], vh = ph[i];
          a1x += __builtin_bit_cast(float, vx.x); a2x += __builtin_bit_cast(float, vx.y);
          a1x += __builtin_bit_cast(float, vx.z); a2x += __builtin_bit_cast(float, vx.w);
          a1h += __builtin_bit_cast(float, vh.x); a2h += __builtin_bit_cast(float, vh.y);
          a1h += __builtin_bit_cast(float, vh.z); a2h += __builtin_bit_cast(float, vh.w);
        }
        float mux = a1x * (1.f / 2048.f), ex2x = a2x * (1.f / 2048.f);
        float muh = a1h * (1.f / 2048.f), ex2h = a2h * (1.f / 2048.f);
        musd[tid] = mux;
        musd[64 + tid] = 1.0f / sqrtf(ex2x - mux * mux + 1e-5f);
        musd[128 + tid] = muh;
        musd[192 + tid] = 1.0f / sqrtf(ex2h - muh * muh + 1e-5f);
      }
      __syncthreads();
      // ---- phase B: gates, state update, publish h ----
#pragma unroll
      for (int j = 0; j < 4; ++j) {
        int r = w * 16 + lq * 4 + j;
        float mux = musd[r], rsx = musd[64 + r], muh = musd[128 + r], rsh = musd[192 + r];
        float gv[4];
#pragma unroll
        for (int q = 0; q < 4; ++q)
          gv[q] = (yx[q][j] - mux) * rsx * gxv[q] + bxv[q] + biv[q] +
                  (yh[q][j] - muh) * rsh * ghv[q] + bhv[q];
        float fi = 1.f / (1.f + expf(-gv[0]));
        float ff = 1.f / (1.f + expf(-gv[1]));
        float fo = 1.f / (1.f + expf(-gv[2]));
        float fu = tanhf(gv[3]);
        cr[j] = ff * cr[j] + fi * fu;
        float h = fo * tanhf(cr[j]);
        hs[j] = h;
        __hip_atomic_store(&myhp[(size_t)r * 512 + hcol], split2(h),
                           __ATOMIC_RELAXED, __HIP_MEMORY_SCOPE_AGENT);
      }
    }
    // ---- barrier 2; output stores overlap the poll ----
    BAR_ARRIVE();
    if (act) {
#pragma unroll
      for (int j = 0; j < 4; ++j) {
        int r = w * 16 + lq * 4 + j;
        size_t ro = (size_t)r * 512 + hcol;
        if (!l0) out[(size_t)t * 32768 + ro] = hs[j];
        if (t == 255) {
          out[8388608 + (size_t)layer * 32768 + ro] = hs[j];
          out[8388608 + 65536 + (size_t)layer * 32768 + ro] = cr[j];
        }
      }
    }
    BAR_WAIT();
    __syncthreads();
  }
#undef BAR_ARRIVE
#undef BAR_WAIT
}

// ---- workspace layout (bytes), total ~50.9 MB ----
#define XS_OFF  0ull         // 256*64*512 u32 packed x = 32MB
#define FRG_OFF 33554432ull  // 8 frag arrays (wh/wx x hi/lo x 2 layers) x 2MB = 16MB
#define HP0_OFF 50331648ull  // 64*512 u32 = 128KB
#define HP1_OFF 50462720ull  // 128KB
#define PRT_OFF 50593792ull  // 2 layer * 2 p * 2 set * 64 row * 32 g * u64 = 256KB
#define FLG_OFF 50855936ull  // 2048 u32 = 8KB

extern "C" void kernel_launch(void* const* d_in, const int* in_sizes, int n_in,
                              void* d_out, int out_size, void* d_ws, size_t ws_size,
                              hipStream_t stream) {
  const float* inputs = (const float*)d_in[0];
  const float* h0 = (const float*)d_in[1];
  const float* c0 = (const float*)d_in[2];
  const float* wx = (const float*)d_in[3];
  const float* wh = (const float*)d_in[4];
  const float* bias = (const float*)d_in[5];
  const float* gxp = (const float*)d_in[6];
  const float* bxp = (const float*)d_in[7];
  const float* ghp = (const float*)d_in[8];
  const float* bhp = (const float*)d_in[9];
  float* out = (float*)d_out;
  char* ws = (char*)d_ws;

  unsigned* xs = (unsigned*)(ws + XS_OFF);
  u16* frg = (u16*)(ws + FRG_OFF);
  unsigned* hp0 = (unsigned*)(ws + HP0_OFF);
  unsigned* hp1 = (unsigned*)(ws + HP1_OFF);
  unsigned long long* prt = (unsigned long long*)(ws + PRT_OFF);
  unsigned* flg = (unsigned*)(ws + FLG_OFF);

  k_zero<<<8, 256, 0, stream>>>(flg);
  k_xsplit<<<4096, 256, 0, stream>>>(inputs, xs, 8388608);
  for (int l = 0; l < 2; ++l) {
    k_pack<<<512, 256, 0, stream>>>(wh + (size_t)l * 1048576,
                                    frg + (size_t)(l * 4 + 0) * 1048576,
                                    frg + (size_t)(l * 4 + 1) * 1048576);
    k_pack<<<512, 256, 0, stream>>>(wx + (size_t)l * 1048576,
                                    frg + (size_t)(l * 4 + 2) * 1048576,
                                    frg + (size_t)(l * 4 + 3) * 1048576);
  }
  k_scan7<<<NWGT, 256, 0, stream>>>(xs, frg, gxp, bxp, ghp, bhp, bias, h0, c0,
                                    hp0, hp1, prt, flg, out);
}